// Round 4
// baseline (221.780 us; speedup 1.0000x reference)
//
#include <hip/hip_runtime.h>

#define D     4096
#define NH    32
#define HD    128
#define TT    8192
#define SINKN 4
#define NC    64
#define CS    128         // keys per chunk
#define ICH   64          // K-split chunks (64 rows each) for all GEMV partials
#define PBSTR (HD + 2)

// ---------------- K1: q partials = x @ Wq; zero out[0:4096] ----------------
// grid = 4 jb * 64 ic = 256 blocks, block = 256
__global__ __launch_bounds__(256) void q_gemv(
        const float* __restrict__ x,
        const float* __restrict__ Wq,
        float* __restrict__ partQ,
        float* __restrict__ out) {
    int bid = blockIdx.x;
    int tid = threadIdx.x;
    if (bid < 16) out[bid * 256 + tid] = 0.f;   // init for K3 atomics
    int jb = bid >> 6;           // 0..3
    int ic = bid & 63;           // 0..63
    int j0 = jb * 1024 + tid * 4;
    int i0 = ic * 64;
    __shared__ float xs[64];
    if (tid < 64) xs[tid] = x[i0 + tid];
    __syncthreads();
    float4 acc = {0.f, 0.f, 0.f, 0.f};
    const float* Wp = Wq + (size_t)i0 * D + j0;
    #pragma unroll 16
    for (int i = 0; i < 64; ++i) {
        float4 w = *(const float4*)Wp;
        float xv = xs[i];
        acc.x += xv * w.x; acc.y += xv * w.y;
        acc.z += xv * w.z; acc.w += xv * w.w;
        Wp += D;
    }
    *(float4*)(partQ + (size_t)ic * D + j0) = acc;
}

// ---------------- K2: mega-kernel — Wk/Wv GEMV partials overlapped with attention ----------------
// grid = 512 (kv GEMV) + NH*NC (attn) = 2560, block = 256
__global__ __launch_bounds__(256) void attn_kv(
        const float* __restrict__ x,
        const float* __restrict__ partQ,
        const float* __restrict__ Wk,
        const float* __restrict__ Wv,
        const float* __restrict__ K,
        const float* __restrict__ V,
        float* __restrict__ newK,
        float* __restrict__ newV,
        float* __restrict__ partKV,
        float* __restrict__ partB) {
    int bid = blockIdx.x;
    int tid = threadIdx.x;

    __shared__ float xs[64];
    __shared__ float qs[HD];
    __shared__ float sc[CS];
    __shared__ float ml[2];
    __shared__ float ctx8[8][HD];

    if (bid < 512) {
        // ---- Wk/Wv GEMV partial blocks ----
        int mat = bid >> 8;          // 0 = K, 1 = V
        int rem = bid & 255;
        int jb  = rem >> 6;          // 0..3
        int ic  = rem & 63;          // 0..63
        const float* Wm = mat ? Wv : Wk;
        int j0 = jb * 1024 + tid * 4;
        int i0 = ic * 64;
        if (tid < 64) xs[tid] = x[i0 + tid];
        __syncthreads();
        float4 acc = {0.f, 0.f, 0.f, 0.f};
        const float* Wp = Wm + (size_t)i0 * D + j0;
        #pragma unroll 16
        for (int i = 0; i < 64; ++i) {
            float4 w = *(const float4*)Wp;
            float xv = xs[i];
            acc.x += xv * w.x; acc.y += xv * w.y;
            acc.z += xv * w.z; acc.w += xv * w.w;
            Wp += D;
        }
        *(float4*)(partKV + (size_t)(mat * ICH + ic) * D + j0) = acc;
        return;
    }

    // ---- attention blocks ----
    int b = bid - 512;
    int h = b >> 6;
    int c = b & 63;
    int t0 = c * CS;
    int wave = tid >> 6;
    int lane = tid & 63;
    int l31  = lane & 31;
    int half = lane >> 5;

    // fused q-reduce: q[d] = sum over 64 partial rows
    {
        int d  = tid & 127;
        int hh = tid >> 7;   // 0/1
        const float* p = partQ + (size_t)(hh * 32) * D + (size_t)h * HD + d;
        float s = 0.f;
        #pragma unroll
        for (int i = 0; i < 32; ++i) s += p[(size_t)i * D];
        ctx8[hh][d] = s;
    }
    __syncthreads();
    if (tid < HD) qs[tid] = ctx8[0][tid] + ctx8[1][tid];
    __syncthreads();

    float4 qv = *(const float4*)(qs + 4 * l31);
    const float scale = 0.08838834764831845f; // 1/sqrt(128)

    const float* Kh = K    + (size_t)h * TT * HD;
    float*      nKh = newK + (size_t)h * TT * HD;
    // pass 1: scores + shifted K write (row r -> r-1 for r>4; drop r==4)
    #pragma unroll 4
    for (int kk = 0; kk < 16; ++kk) {
        int r = t0 + kk * 8 + wave * 2 + half;
        float4 kv = *(const float4*)(Kh + (size_t)r * HD + 4 * l31);
        if (r != SINKN) {
            int dst = (r < SINKN) ? r : r - 1;
            *(float4*)(nKh + (size_t)dst * HD + 4 * l31) = kv;
        }
        float p = qv.x * kv.x + qv.y * kv.y + qv.z * kv.z + qv.w * kv.w;
        p += __shfl_xor(p, 16, 64);
        p += __shfl_xor(p, 8, 64);
        p += __shfl_xor(p, 4, 64);
        p += __shfl_xor(p, 2, 64);
        p += __shfl_xor(p, 1, 64);
        if (l31 == 0) sc[r - t0] = p * scale;
    }
    __syncthreads();
    // chunk-local softmax (wave 0)
    if (wave == 0) {
        float s0 = sc[lane], s1 = sc[lane + 64];
        float m = fmaxf(s0, s1);
        #pragma unroll
        for (int off = 32; off; off >>= 1) m = fmaxf(m, __shfl_xor(m, off, 64));
        float w0 = __expf(s0 - m), w1 = __expf(s1 - m);
        sc[lane] = w0; sc[lane + 64] = w1;
        float l = w0 + w1;
        #pragma unroll
        for (int off = 32; off; off >>= 1) l += __shfl_xor(l, off, 64);
        if (lane == 0) { ml[0] = m; ml[1] = l; }
    }
    __syncthreads();
    // pass 2: weighted V sum + shifted V write
    const float* Vh = V    + (size_t)h * TT * HD;
    float*      nVh = newV + (size_t)h * TT * HD;
    float a0 = 0.f, a1 = 0.f, a2 = 0.f, a3 = 0.f;
    #pragma unroll 4
    for (int kk = 0; kk < 16; ++kk) {
        int r = t0 + kk * 8 + wave * 2 + half;
        float4 vv = *(const float4*)(Vh + (size_t)r * HD + 4 * l31);
        if (r != SINKN) {
            int dst = (r < SINKN) ? r : r - 1;
            *(float4*)(nVh + (size_t)dst * HD + 4 * l31) = vv;
        }
        float w = sc[r - t0];
        a0 += w * vv.x; a1 += w * vv.y; a2 += w * vv.z; a3 += w * vv.w;
    }
    int g = wave * 2 + half;
    ctx8[g][4 * l31 + 0] = a0;
    ctx8[g][4 * l31 + 1] = a1;
    ctx8[g][4 * l31 + 2] = a2;
    ctx8[g][4 * l31 + 3] = a3;
    __syncthreads();
    float* pbE = partB + ((size_t)h * NC + c) * PBSTR;
    if (tid < HD) {
        float s = 0.f;
        #pragma unroll
        for (int gg = 0; gg < 8; ++gg) s += ctx8[gg][tid];
        pbE[2 + tid] = s;
    }
    if (tid == 0) { pbE[0] = ml[0]; pbE[1] = ml[1]; }
}

// ---------------- K3: finalize k/v_new + combine + out GEMV (atomic reduce) ----------------
// grid = 8 jb * 64 ic = 512 blocks, block = 128
__global__ __launch_bounds__(128) void out_fused(
        const float* __restrict__ partQ,
        const float* __restrict__ partKV,
        const float* __restrict__ partB,
        const float* __restrict__ Wo,
        float* __restrict__ newK,
        float* __restrict__ newV,
        float* __restrict__ out) {
    int bid = blockIdx.x;
    int jb = bid >> 6;       // 0..7
    int ic = bid & 63;       // 0..63
    int tid = threadIdx.x;   // 0..127
    int h  = ic >> 1;
    int d0 = (ic & 1) * 64;

    // per-head reduce of q, k_new, v_new at dim tid (L2-resident partials)
    const float* pq = partQ  + (size_t)h * HD + tid;
    const float* pk = partKV + (size_t)h * HD + tid;
    const float* pv = partKV + (size_t)ICH * D + (size_t)h * HD + tid;
    float qd = 0.f, kd = 0.f, vd = 0.f;
    #pragma unroll
    for (int i = 0; i < ICH; ++i) {
        qd += pq[(size_t)i * D];
        kd += pk[(size_t)i * D];
        vd += pv[(size_t)i * D];
    }
    if (jb == 0 && (ic & 1) == 0) {
        newK[((size_t)h * TT + (TT - 1)) * HD + tid] = kd;
        newV[((size_t)h * TT + (TT - 1)) * HD + tid] = vd;
    }

    __shared__ float red[HD];
    __shared__ float vsh[HD];
    __shared__ float marr[NC], larr[NC], wgt[NC + 1];
    __shared__ float ctxs[64];
    __shared__ float Ls;

    vsh[tid] = vd;
    red[tid] = qd * kd;
    __syncthreads();
    for (int s = 64; s > 0; s >>= 1) {
        if (tid < s) red[tid] += red[tid + s];
        __syncthreads();
    }
    float s_new = red[0] * 0.08838834764831845f;

    const float* pb = partB + (size_t)h * NC * PBSTR;
    if (tid < NC) {
        marr[tid] = pb[tid * PBSTR];
        larr[tid] = pb[tid * PBSTR + 1];
    }
    __syncthreads();
    float M = s_new;
    #pragma unroll
    for (int cc = 0; cc < NC; ++cc) M = fmaxf(M, marr[cc]);
    if (tid < NC) wgt[tid] = __expf(marr[tid] - M);
    else if (tid == NC) wgt[NC] = __expf(s_new - M);
    __syncthreads();
    if (tid < 64) {
        float s = wgt[tid] * larr[tid] + ((tid == 0) ? wgt[NC] : 0.f);
        #pragma unroll
        for (int off = 32; off; off >>= 1) s += __shfl_xor(s, off, 64);
        if (tid == 0) Ls = s;
    }
    __syncthreads();
    if (tid < 64) {
        const float* pc = pb + 2 + d0 + tid;
        float acc = wgt[NC] * vsh[d0 + tid];
        #pragma unroll
        for (int cc = 0; cc < NC; ++cc) acc += wgt[cc] * pc[cc * PBSTR];
        ctxs[tid] = acc / Ls;
    }
    __syncthreads();

    int j0 = jb * 512 + tid * 4;
    float4 acc = {0.f, 0.f, 0.f, 0.f};
    const float* Wp = Wo + (size_t)(ic * 64) * D + j0;
    #pragma unroll 16
    for (int i = 0; i < 64; ++i) {
        float4 w = *(const float4*)Wp;
        float xv = ctxs[i];
        acc.x += xv * w.x; acc.y += xv * w.y;
        acc.z += xv * w.z; acc.w += xv * w.w;
        Wp += D;
    }
    atomicAdd(&out[j0 + 0], acc.x);
    atomicAdd(&out[j0 + 1], acc.y);
    atomicAdd(&out[j0 + 2], acc.z);
    atomicAdd(&out[j0 + 3], acc.w);
}

extern "C" void kernel_launch(void* const* d_in, const int* in_sizes, int n_in,
                              void* d_out, int out_size, void* d_ws, size_t ws_size,
                              hipStream_t stream) {
    const float* x  = (const float*)d_in[0];
    const float* cK = (const float*)d_in[1];
    const float* cV = (const float*)d_in[2];
    const float* Wq = (const float*)d_in[3];
    const float* Wk = (const float*)d_in[4];
    const float* Wv = (const float*)d_in[5];
    const float* Wo = (const float*)d_in[6];

    float* out  = (float*)d_out;
    float* newK = out + D;
    float* newV = newK + (size_t)NH * TT * HD;

    float* ws     = (float*)d_ws;
    float* partQ  = ws;                          // ICH*D floats   (1 MB)
    float* partKV = partQ + (size_t)ICH * D;     // 2*ICH*D floats (2 MB)
    float* partB  = partKV + (size_t)2 * ICH * D;// NH*NC*PBSTR    (~1 MB)

    q_gemv   <<<256,        256, 0, stream>>>(x, Wq, partQ, out);
    attn_kv  <<<512 + NH*NC,256, 0, stream>>>(x, partQ, Wk, Wv, cK, cV,
                                              newK, newV, partKV, partB);
    out_fused<<<512,        128, 0, stream>>>(partQ, partKV, partB, Wo,
                                              newK, newV, out);
}

// Round 5
// 202.069 us; speedup vs baseline: 1.0975x; 1.0975x over previous
//
#include <hip/hip_runtime.h>

#define D     4096
#define NH    32
#define HD    128
#define TT    8192
#define SINKN 4
#define NC    64
#define CS    128         // keys per chunk
#define ICH   64          // K-split chunks (64 rows each) for all GEMV partials
#define PBSTR (HD + 2)

// ---------------- K1: q partials = x @ Wq; zero out[0:4096] ----------------
// grid = 4 jb * 64 ic = 256 blocks, block = 256
__global__ __launch_bounds__(256) void q_gemv(
        const float* __restrict__ x,
        const float* __restrict__ Wq,
        float* __restrict__ partQ,
        float* __restrict__ out) {
    int bid = blockIdx.x;
    int tid = threadIdx.x;
    if (bid < 16) out[bid * 256 + tid] = 0.f;   // init for K3 atomics
    int jb = bid >> 6;           // 0..3
    int ic = bid & 63;           // 0..63
    int j0 = jb * 1024 + tid * 4;
    int i0 = ic * 64;
    __shared__ float xs[64];
    if (tid < 64) xs[tid] = x[i0 + tid];
    __syncthreads();
    float4 acc = {0.f, 0.f, 0.f, 0.f};
    const float* Wp = Wq + (size_t)i0 * D + j0;
    #pragma unroll 16
    for (int i = 0; i < 64; ++i) {
        float4 w = *(const float4*)Wp;
        float xv = xs[i];
        acc.x += xv * w.x; acc.y += xv * w.y;
        acc.z += xv * w.z; acc.w += xv * w.w;
        Wp += D;
    }
    *(float4*)(partQ + (size_t)ic * D + j0) = acc;
}

// ---------------- K2: attention (bids 0..2047, R3-verbatim loops) + Wk/Wv GEMV tail (bids 2048..2559) ----------------
__global__ __launch_bounds__(256) void attn_kv(
        const float* __restrict__ x,
        const float* __restrict__ partQ,
        const float* __restrict__ Wk,
        const float* __restrict__ Wv,
        const float* __restrict__ K,
        const float* __restrict__ V,
        float* __restrict__ newK,
        float* __restrict__ newV,
        float* __restrict__ partKV,
        float* __restrict__ partB) {
    int bid = blockIdx.x;
    int tid = threadIdx.x;

    __shared__ float xs[64];
    __shared__ float qs[HD];
    __shared__ float sc[CS];
    __shared__ float ml[2];
    __shared__ float ctx8[8][HD];

    if (bid >= 2048) {
        // ---- Wk/Wv GEMV partial blocks (tail bids: backfill as attn retires) ----
        int b2  = bid - 2048;
        int mat = b2 >> 8;           // 0 = K, 1 = V
        int rem = b2 & 255;
        int jb  = rem >> 6;          // 0..3
        int ic  = rem & 63;          // 0..63
        const float* Wm = mat ? Wv : Wk;
        int j0 = jb * 1024 + tid * 4;
        int i0 = ic * 64;
        if (tid < 64) xs[tid] = x[i0 + tid];
        __syncthreads();
        float4 acc = {0.f, 0.f, 0.f, 0.f};
        const float* Wp = Wm + (size_t)i0 * D + j0;
        #pragma unroll 16
        for (int i = 0; i < 64; ++i) {
            float4 w = *(const float4*)Wp;
            float xv = xs[i];
            acc.x += xv * w.x; acc.y += xv * w.y;
            acc.z += xv * w.z; acc.w += xv * w.w;
            Wp += D;
        }
        *(float4*)(partKV + (size_t)(mat * ICH + ic) * D + j0) = acc;
        return;
    }

    // ---- attention blocks (R3-verbatim) ----
    int h = bid >> 6;
    int c = bid & 63;
    int t0 = c * CS;
    int wave = tid >> 6;
    int lane = tid & 63;
    int l31  = lane & 31;
    int half = lane >> 5;

    // fused q-reduce: q[d] = sum over 64 partial rows
    {
        int d  = tid & 127;
        int hh = tid >> 7;   // 0/1
        const float* p = partQ + (size_t)(hh * 32) * D + (size_t)h * HD + d;
        float s = 0.f;
        #pragma unroll
        for (int i = 0; i < 32; ++i) s += p[(size_t)i * D];
        ctx8[hh][d] = s;
    }
    __syncthreads();
    if (tid < HD) qs[tid] = ctx8[0][tid] + ctx8[1][tid];
    __syncthreads();

    float4 qv = *(const float4*)(qs + 4 * l31);
    const float scale = 0.08838834764831845f; // 1/sqrt(128)

    const float* Kh = K    + (size_t)h * TT * HD;
    float*      nKh = newK + (size_t)h * TT * HD;
    // pass 1: scores + shifted K write (row r -> r-1 for r>4; drop r==4)
    for (int kk = 0; kk < 16; ++kk) {
        int r = t0 + kk * 8 + wave * 2 + half;
        float4 kv = *(const float4*)(Kh + (size_t)r * HD + 4 * l31);
        float p = qv.x * kv.x + qv.y * kv.y + qv.z * kv.z + qv.w * kv.w;
        p += __shfl_xor(p, 16, 64);
        p += __shfl_xor(p, 8, 64);
        p += __shfl_xor(p, 4, 64);
        p += __shfl_xor(p, 2, 64);
        p += __shfl_xor(p, 1, 64);
        if (l31 == 0) sc[r - t0] = p * scale;
        if (r != SINKN) {
            int dst = (r < SINKN) ? r : r - 1;
            *(float4*)(nKh + (size_t)dst * HD + 4 * l31) = kv;
        }
    }
    __syncthreads();
    // chunk-local softmax (wave 0)
    if (wave == 0) {
        float s0 = sc[lane], s1 = sc[lane + 64];
        float m = fmaxf(s0, s1);
        #pragma unroll
        for (int off = 32; off; off >>= 1) m = fmaxf(m, __shfl_xor(m, off, 64));
        float w0 = __expf(s0 - m), w1 = __expf(s1 - m);
        sc[lane] = w0; sc[lane + 64] = w1;
        float l = w0 + w1;
        #pragma unroll
        for (int off = 32; off; off >>= 1) l += __shfl_xor(l, off, 64);
        if (lane == 0) { ml[0] = m; ml[1] = l; }
    }
    __syncthreads();
    // pass 2: weighted V sum + shifted V write
    const float* Vh = V    + (size_t)h * TT * HD;
    float*      nVh = newV + (size_t)h * TT * HD;
    float a0 = 0.f, a1 = 0.f, a2 = 0.f, a3 = 0.f;
    for (int kk = 0; kk < 16; ++kk) {
        int r = t0 + kk * 8 + wave * 2 + half;
        float4 vv = *(const float4*)(Vh + (size_t)r * HD + 4 * l31);
        float w = sc[r - t0];
        a0 += w * vv.x; a1 += w * vv.y; a2 += w * vv.z; a3 += w * vv.w;
        if (r != SINKN) {
            int dst = (r < SINKN) ? r : r - 1;
            *(float4*)(nVh + (size_t)dst * HD + 4 * l31) = vv;
        }
    }
    int g = wave * 2 + half;
    ctx8[g][4 * l31 + 0] = a0;
    ctx8[g][4 * l31 + 1] = a1;
    ctx8[g][4 * l31 + 2] = a2;
    ctx8[g][4 * l31 + 3] = a3;
    __syncthreads();
    float* pbE = partB + ((size_t)h * NC + c) * PBSTR;
    if (tid < HD) {
        float s = 0.f;
        #pragma unroll
        for (int gg = 0; gg < 8; ++gg) s += ctx8[gg][tid];
        pbE[2 + tid] = s;
    }
    if (tid == 0) { pbE[0] = ml[0]; pbE[1] = ml[1]; }
}

// ---------------- K3: finalize k/v_new + combine + out GEMV (atomic reduce) ----------------
// grid = 8 jb * 64 ic = 512 blocks, block = 128
__global__ __launch_bounds__(128) void out_fused(
        const float* __restrict__ partQ,
        const float* __restrict__ partKV,
        const float* __restrict__ partB,
        const float* __restrict__ Wo,
        float* __restrict__ newK,
        float* __restrict__ newV,
        float* __restrict__ out) {
    int bid = blockIdx.x;
    int jb = bid >> 6;       // 0..7
    int ic = bid & 63;       // 0..63
    int tid = threadIdx.x;   // 0..127
    int h  = ic >> 1;
    int d0 = (ic & 1) * 64;

    // per-head reduce of q, k_new, v_new at dim tid (L2-resident partials)
    const float* pq = partQ  + (size_t)h * HD + tid;
    const float* pk = partKV + (size_t)h * HD + tid;
    const float* pv = partKV + (size_t)ICH * D + (size_t)h * HD + tid;
    float qd = 0.f, kd = 0.f, vd = 0.f;
    #pragma unroll
    for (int i = 0; i < ICH; ++i) {
        qd += pq[(size_t)i * D];
        kd += pk[(size_t)i * D];
        vd += pv[(size_t)i * D];
    }
    if (jb == 0 && (ic & 1) == 0) {
        newK[((size_t)h * TT + (TT - 1)) * HD + tid] = kd;
        newV[((size_t)h * TT + (TT - 1)) * HD + tid] = vd;
    }

    __shared__ float red[HD];
    __shared__ float vsh[HD];
    __shared__ float marr[NC], larr[NC], wgt[NC + 1];
    __shared__ float ctxs[64];
    __shared__ float Ls;

    vsh[tid] = vd;
    red[tid] = qd * kd;
    __syncthreads();
    for (int s = 64; s > 0; s >>= 1) {
        if (tid < s) red[tid] += red[tid + s];
        __syncthreads();
    }
    float s_new = red[0] * 0.08838834764831845f;

    const float* pb = partB + (size_t)h * NC * PBSTR;
    if (tid < NC) {
        marr[tid] = pb[tid * PBSTR];
        larr[tid] = pb[tid * PBSTR + 1];
    }
    __syncthreads();
    float M = s_new;
    #pragma unroll
    for (int cc = 0; cc < NC; ++cc) M = fmaxf(M, marr[cc]);
    if (tid < NC) wgt[tid] = __expf(marr[tid] - M);
    else if (tid == NC) wgt[NC] = __expf(s_new - M);
    __syncthreads();
    if (tid < 64) {
        float s = wgt[tid] * larr[tid] + ((tid == 0) ? wgt[NC] : 0.f);
        #pragma unroll
        for (int off = 32; off; off >>= 1) s += __shfl_xor(s, off, 64);
        if (tid == 0) Ls = s;
    }
    __syncthreads();
    if (tid < 64) {
        const float* pc = pb + 2 + d0 + tid;
        float acc = wgt[NC] * vsh[d0 + tid];
        #pragma unroll
        for (int cc = 0; cc < NC; ++cc) acc += wgt[cc] * pc[cc * PBSTR];
        ctxs[tid] = acc / Ls;
    }
    __syncthreads();

    int j0 = jb * 512 + tid * 4;
    float4 acc = {0.f, 0.f, 0.f, 0.f};
    const float* Wp = Wo + (size_t)(ic * 64) * D + j0;
    #pragma unroll 16
    for (int i = 0; i < 64; ++i) {
        float4 w = *(const float4*)Wp;
        float xv = ctxs[i];
        acc.x += xv * w.x; acc.y += xv * w.y;
        acc.z += xv * w.z; acc.w += xv * w.w;
        Wp += D;
    }
    atomicAdd(&out[j0 + 0], acc.x);
    atomicAdd(&out[j0 + 1], acc.y);
    atomicAdd(&out[j0 + 2], acc.z);
    atomicAdd(&out[j0 + 3], acc.w);
}

extern "C" void kernel_launch(void* const* d_in, const int* in_sizes, int n_in,
                              void* d_out, int out_size, void* d_ws, size_t ws_size,
                              hipStream_t stream) {
    const float* x  = (const float*)d_in[0];
    const float* cK = (const float*)d_in[1];
    const float* cV = (const float*)d_in[2];
    const float* Wq = (const float*)d_in[3];
    const float* Wk = (const float*)d_in[4];
    const float* Wv = (const float*)d_in[5];
    const float* Wo = (const float*)d_in[6];

    float* out  = (float*)d_out;
    float* newK = out + D;
    float* newV = newK + (size_t)NH * TT * HD;

    float* ws     = (float*)d_ws;
    float* partQ  = ws;                          // ICH*D floats   (1 MB)
    float* partKV = partQ + (size_t)ICH * D;     // 2*ICH*D floats (2 MB)
    float* partB  = partKV + (size_t)2 * ICH * D;// NH*NC*PBSTR    (~1 MB)

    q_gemv   <<<256,         256, 0, stream>>>(x, Wq, partQ, out);
    attn_kv  <<<2048 + 512,  256, 0, stream>>>(x, partQ, Wk, Wv, cK, cV,
                                               newK, newV, partKV, partB);
    out_fused<<<512,         128, 0, stream>>>(partQ, partKV, partB, Wo,
                                               newK, newV, out);
}

// Round 7
// 171.687 us; speedup vs baseline: 1.2918x; 1.1770x over previous
//
#include <hip/hip_runtime.h>

#define D     4096
#define NH    32
#define HD    128
#define TT    8192
#define SINKN 4
#define NC    64
#define CS    128         // keys per chunk
#define ICH   64          // K-split chunks for qkv GEMV (64 rows each)
#define PBSTR (HD + 2)

typedef float f4v __attribute__((ext_vector_type(4)));

// ---------------- K1: q/k/v partials = x @ {Wq,Wk,Wv}; zero out[0:4096] ----------------
// grid = 3 * 4 jb * 64 ic = 768 blocks, block = 256
__global__ __launch_bounds__(256) void qkv_partial(
        const float* __restrict__ x,
        const float* __restrict__ Wq,
        const float* __restrict__ Wk,
        const float* __restrict__ Wv,
        float* __restrict__ partA,
        float* __restrict__ out) {
    int bid = blockIdx.x;
    int tid = threadIdx.x;
    if (bid < 16) out[bid * 256 + tid] = 0.f;   // init for K3 atomics
    int mat = bid >> 8;          // 0..2
    int rem = bid & 255;
    int jb  = rem >> 6;          // 0..3
    int ic  = rem & 63;          // 0..63
    const float* Wm = (mat == 0) ? Wq : (mat == 1) ? Wk : Wv;
    int j0 = jb * 1024 + tid * 4;
    int i0 = ic * 64;
    __shared__ float xs[64];
    if (tid < 64) xs[tid] = x[i0 + tid];
    __syncthreads();
    float4 acc = {0.f, 0.f, 0.f, 0.f};
    const float* Wp = Wm + (size_t)i0 * D + j0;
    #pragma unroll 16
    for (int i = 0; i < 64; ++i) {
        float4 w = *(const float4*)Wp;
        float xv = xs[i];
        acc.x += xv * w.x; acc.y += xv * w.y;
        acc.z += xv * w.z; acc.w += xv * w.w;
        Wp += D;
    }
    *(float4*)(partA + (size_t)(mat * ICH + ic) * D + j0) = acc;
}

// ---------------- K2: attention partials + q-reduce + evict shift (NT stores) + new-token entry ----------------
// grid = NH*NC = 2048 (8 blocks/CU), block = 256
__global__ __launch_bounds__(256) void attn_chunk(
        const float* __restrict__ partA,
        const float* __restrict__ K,
        const float* __restrict__ V,
        float* __restrict__ newK,
        float* __restrict__ newV,
        float* __restrict__ partB) {
    int bid = blockIdx.x;
    int h = bid >> 6;
    int c = bid & 63;
    int t0 = c * CS;
    int tid  = threadIdx.x;
    int wave = tid >> 6;
    int lane = tid & 63;
    int l31  = lane & 31;
    int half = lane >> 5;

    __shared__ float qs[HD];
    __shared__ float sc[CS];
    __shared__ float ml[2];
    __shared__ float ctx8[8][HD];

    // fused q-reduce: q[d] = sum over 64 partial rows
    {
        int d  = tid & 127;
        int hh = tid >> 7;   // 0/1 -> halves of the 64 chunks
        const float* p = partA + (size_t)(hh * 32) * D + (size_t)h * HD + d;
        float s = 0.f;
        #pragma unroll
        for (int i = 0; i < 32; ++i) s += p[(size_t)i * D];
        ctx8[hh][d] = s;
    }
    __syncthreads();
    if (tid < HD) qs[tid] = ctx8[0][tid] + ctx8[1][tid];
    __syncthreads();

    float4 qv = *(const float4*)(qs + 4 * l31);
    const float scale = 0.08838834764831845f; // 1/sqrt(128)

    const float* Kh = K    + (size_t)h * TT * HD;
    float*      nKh = newK + (size_t)h * TT * HD;
    // pass 1: scores + shifted K write (row r -> r-1 for r>4; drop r==4)
    for (int kk = 0; kk < 16; ++kk) {
        int r = t0 + kk * 8 + wave * 2 + half;
        float4 kv = *(const float4*)(Kh + (size_t)r * HD + 4 * l31);
        float p = qv.x * kv.x + qv.y * kv.y + qv.z * kv.z + qv.w * kv.w;
        p += __shfl_xor(p, 16, 64);
        p += __shfl_xor(p, 8, 64);
        p += __shfl_xor(p, 4, 64);
        p += __shfl_xor(p, 2, 64);
        p += __shfl_xor(p, 1, 64);
        if (l31 == 0) sc[r - t0] = p * scale;
        if (r != SINKN) {
            int dst = (r < SINKN) ? r : r - 1;
            f4v kvv = {kv.x, kv.y, kv.z, kv.w};
            __builtin_nontemporal_store(kvv, (f4v*)(nKh + (size_t)dst * HD + 4 * l31));
        }
    }
    __syncthreads();
    // chunk-local softmax (wave 0)
    if (wave == 0) {
        float s0 = sc[lane], s1 = sc[lane + 64];
        float m = fmaxf(s0, s1);
        #pragma unroll
        for (int off = 32; off; off >>= 1) m = fmaxf(m, __shfl_xor(m, off, 64));
        float w0 = __expf(s0 - m), w1 = __expf(s1 - m);
        sc[lane] = w0; sc[lane + 64] = w1;
        float l = w0 + w1;
        #pragma unroll
        for (int off = 32; off; off >>= 1) l += __shfl_xor(l, off, 64);
        if (lane == 0) { ml[0] = m; ml[1] = l; }
    }
    __syncthreads();
    // pass 2: weighted V sum + shifted V write
    const float* Vh = V    + (size_t)h * TT * HD;
    float*      nVh = newV + (size_t)h * TT * HD;
    float a0 = 0.f, a1 = 0.f, a2 = 0.f, a3 = 0.f;
    for (int kk = 0; kk < 16; ++kk) {
        int r = t0 + kk * 8 + wave * 2 + half;
        float4 vv = *(const float4*)(Vh + (size_t)r * HD + 4 * l31);
        float w = sc[r - t0];
        a0 += w * vv.x; a1 += w * vv.y; a2 += w * vv.z; a3 += w * vv.w;
        if (r != SINKN) {
            int dst = (r < SINKN) ? r : r - 1;
            f4v vvv = {vv.x, vv.y, vv.z, vv.w};
            __builtin_nontemporal_store(vvv, (f4v*)(nVh + (size_t)dst * HD + 4 * l31));
        }
    }
    int g = wave * 2 + half;
    ctx8[g][4 * l31 + 0] = a0;
    ctx8[g][4 * l31 + 1] = a1;
    ctx8[g][4 * l31 + 2] = a2;
    ctx8[g][4 * l31 + 3] = a3;
    __syncthreads();
    float* pbE = partB + ((size_t)h * (NC + 1) + c) * PBSTR;
    if (tid < HD) {
        float s = 0.f;
        #pragma unroll
        for (int gg = 0; gg < 8; ++gg) s += ctx8[gg][tid];
        pbE[2 + tid] = s;
    }
    if (tid == 0) { pbE[0] = ml[0]; pbE[1] = ml[1]; }

    // c==0 blocks: reduce k_new/v_new, write cache slot TT-1, emit 65th entry
    if (c == 0) {
        float kd = 0.f, vd = 0.f;
        if (tid < HD) {
            const float* pk = partA + (size_t)(ICH) * D + (size_t)h * HD + tid;
            const float* pv = partA + (size_t)(2 * ICH) * D + (size_t)h * HD + tid;
            #pragma unroll
            for (int i = 0; i < ICH; ++i) {
                kd += pk[(size_t)i * D];
                vd += pv[(size_t)i * D];
            }
            __builtin_nontemporal_store(kd, newK + ((size_t)h * TT + (TT - 1)) * HD + tid);
            __builtin_nontemporal_store(vd, newV + ((size_t)h * TT + (TT - 1)) * HD + tid);
        }
        __syncthreads();             // ctx8 reads above are done; safe to reuse
        if (tid < HD) ctx8[0][tid] = qs[tid] * kd;
        __syncthreads();
        float* pbN = partB + ((size_t)h * (NC + 1) + NC) * PBSTR;
        if (tid < 64) {
            float s = ctx8[0][tid] + ctx8[0][tid + 64];
            #pragma unroll
            for (int off = 32; off; off >>= 1) s += __shfl_xor(s, off, 64);
            if (tid == 0) { pbN[0] = s * scale; pbN[1] = 1.0f; }
        }
        if (tid < HD) pbN[2 + tid] = vd;
    }
}

// ---------------- K3: fused combine-slice + out GEMV with atomic reduce ----------------
// grid = 8 jb * 64 ic = 512 blocks, block = 128
__global__ __launch_bounds__(128) void out_fused(
        const float* __restrict__ partB,
        const float* __restrict__ Wo,
        float* __restrict__ out) {
    int bid = blockIdx.x;
    int jb = bid >> 6;       // 0..7
    int ic = bid & 63;       // 0..63
    int tid = threadIdx.x;   // 0..127
    int h  = ic >> 1;        // rows [ic*64, ic*64+64) sit in one head
    int d0 = (ic & 1) * 64;

    __shared__ float marr[NC + 1], larr[NC + 1], wgt[NC + 1];
    __shared__ float ctx[64];
    __shared__ float Ls;

    const float* pb = partB + (size_t)h * (NC + 1) * PBSTR;
    if (tid <= NC) {
        marr[tid] = pb[tid * PBSTR];
        larr[tid] = pb[tid * PBSTR + 1];
    }
    __syncthreads();
    float M = marr[0];
    #pragma unroll
    for (int cc = 1; cc <= NC; ++cc) M = fmaxf(M, marr[cc]);
    if (tid <= NC) wgt[tid] = __expf(marr[tid] - M);
    __syncthreads();
    if (tid < 64) {
        float s = wgt[tid] * larr[tid] + ((tid == 0) ? wgt[NC] * larr[NC] : 0.f);
        #pragma unroll
        for (int off = 32; off; off >>= 1) s += __shfl_xor(s, off, 64);
        if (tid == 0) Ls = s;
    }
    __syncthreads();
    if (tid < 64) {
        const float* pc = pb + 2 + d0 + tid;
        float acc = 0.f;
        #pragma unroll
        for (int cc = 0; cc <= NC; ++cc) acc += wgt[cc] * pc[cc * PBSTR];
        ctx[tid] = acc / Ls;
    }
    __syncthreads();

    int j0 = jb * 512 + tid * 4;
    float4 acc = {0.f, 0.f, 0.f, 0.f};
    const float* Wp = Wo + (size_t)(ic * 64) * D + j0;
    #pragma unroll 16
    for (int i = 0; i < 64; ++i) {
        float4 w = *(const float4*)Wp;
        float xv = ctx[i];
        acc.x += xv * w.x; acc.y += xv * w.y;
        acc.z += xv * w.z; acc.w += xv * w.w;
        Wp += D;
    }
    atomicAdd(&out[j0 + 0], acc.x);
    atomicAdd(&out[j0 + 1], acc.y);
    atomicAdd(&out[j0 + 2], acc.z);
    atomicAdd(&out[j0 + 3], acc.w);
}

extern "C" void kernel_launch(void* const* d_in, const int* in_sizes, int n_in,
                              void* d_out, int out_size, void* d_ws, size_t ws_size,
                              hipStream_t stream) {
    const float* x  = (const float*)d_in[0];
    const float* cK = (const float*)d_in[1];
    const float* cV = (const float*)d_in[2];
    const float* Wq = (const float*)d_in[3];
    const float* Wk = (const float*)d_in[4];
    const float* Wv = (const float*)d_in[5];
    const float* Wo = (const float*)d_in[6];

    float* out  = (float*)d_out;
    float* newK = out + D;
    float* newV = newK + (size_t)NH * TT * HD;

    float* ws    = (float*)d_ws;
    float* partA = ws;                       // 3*ICH*D floats = 3 MB
    float* partB = partA + 3 * ICH * D;      // NH*(NC+1)*PBSTR

    qkv_partial<<<768,     256, 0, stream>>>(x, Wq, Wk, Wv, partA, out);
    attn_chunk <<<NH * NC, 256, 0, stream>>>(partA, cK, cV, newK, newV, partB);
    out_fused  <<<512,     128, 0, stream>>>(partB, Wo, out);
}

// Round 8
// 158.233 us; speedup vs baseline: 1.4016x; 1.0850x over previous
//
#include <hip/hip_runtime.h>

#define D     4096
#define NH    32
#define HD    128
#define TT    8192
#define SINKN 4
#define NC    64
#define CS    128         // keys per chunk
#define ICH   64          // K-split chunks for qkv GEMV (64 rows each)
#define PBSTR (HD + 2)

typedef float f4v __attribute__((ext_vector_type(4)));

// ---------------- K1: q/k/v partials = x @ {Wq,Wk,Wv}; zero out[0:4096] ----------------
// grid = 3 * 4 jb * 64 ic = 768 blocks, block = 256
__global__ __launch_bounds__(256) void qkv_partial(
        const float* __restrict__ x,
        const float* __restrict__ Wq,
        const float* __restrict__ Wk,
        const float* __restrict__ Wv,
        float* __restrict__ partA,
        float* __restrict__ out) {
    int bid = blockIdx.x;
    int tid = threadIdx.x;
    if (bid < 16) out[bid * 256 + tid] = 0.f;   // init for K3 atomics
    int mat = bid >> 8;          // 0..2
    int rem = bid & 255;
    int jb  = rem >> 6;          // 0..3
    int ic  = rem & 63;          // 0..63
    const float* Wm = (mat == 0) ? Wq : (mat == 1) ? Wk : Wv;
    int j0 = jb * 1024 + tid * 4;
    int i0 = ic * 64;
    __shared__ float xs[64];
    if (tid < 64) xs[tid] = x[i0 + tid];
    __syncthreads();
    float4 acc = {0.f, 0.f, 0.f, 0.f};
    const float* Wp = Wm + (size_t)i0 * D + j0;
    #pragma unroll 16
    for (int i = 0; i < 64; ++i) {
        float4 w = *(const float4*)Wp;
        float xv = xs[i];
        acc.x += xv * w.x; acc.y += xv * w.y;
        acc.z += xv * w.z; acc.w += xv * w.w;
        Wp += D;
    }
    *(float4*)(partA + (size_t)(mat * ICH + ic) * D + j0) = acc;
}

// ---------------- K2: attention partials + q-reduce + evict shift (NT load + NT store) ----------------
// grid = NH*NC = 2048 (8 blocks/CU), block = 256
__global__ __launch_bounds__(256) void attn_chunk(
        const float* __restrict__ partA,
        const float* __restrict__ K,
        const float* __restrict__ V,
        float* __restrict__ newK,
        float* __restrict__ newV,
        float* __restrict__ partB) {
    int bid = blockIdx.x;
    int h = bid >> 6;
    int c = bid & 63;
    int t0 = c * CS;
    int tid  = threadIdx.x;
    int wave = tid >> 6;
    int lane = tid & 63;
    int l31  = lane & 31;
    int half = lane >> 5;

    __shared__ float qs[HD];
    __shared__ float sc[CS];
    __shared__ float ml[2];
    __shared__ float ctx8[8][HD];

    // fused q-reduce: q[d] = sum over 64 partial rows
    {
        int d  = tid & 127;
        int hh = tid >> 7;   // 0/1 -> halves of the 64 chunks
        const float* p = partA + (size_t)(hh * 32) * D + (size_t)h * HD + d;
        float s = 0.f;
        #pragma unroll
        for (int i = 0; i < 32; ++i) s += p[(size_t)i * D];
        ctx8[hh][d] = s;
    }
    __syncthreads();
    if (tid < HD) qs[tid] = ctx8[0][tid] + ctx8[1][tid];
    __syncthreads();

    float4 qv = *(const float4*)(qs + 4 * l31);
    const float scale = 0.08838834764831845f; // 1/sqrt(128)

    const float* Kh = K    + (size_t)h * TT * HD;
    float*      nKh = newK + (size_t)h * TT * HD;
    // pass 1: scores + shifted K write (row r -> r-1 for r>4; drop r==4)
    for (int kk = 0; kk < 16; ++kk) {
        int r = t0 + kk * 8 + wave * 2 + half;
        f4v kv = __builtin_nontemporal_load((const f4v*)(Kh + (size_t)r * HD + 4 * l31));
        float p = qv.x * kv.x + qv.y * kv.y + qv.z * kv.z + qv.w * kv.w;
        p += __shfl_xor(p, 16, 64);
        p += __shfl_xor(p, 8, 64);
        p += __shfl_xor(p, 4, 64);
        p += __shfl_xor(p, 2, 64);
        p += __shfl_xor(p, 1, 64);
        if (l31 == 0) sc[r - t0] = p * scale;
        if (r != SINKN) {
            int dst = (r < SINKN) ? r : r - 1;
            __builtin_nontemporal_store(kv, (f4v*)(nKh + (size_t)dst * HD + 4 * l31));
        }
    }
    __syncthreads();
    // chunk-local softmax (wave 0)
    if (wave == 0) {
        float s0 = sc[lane], s1 = sc[lane + 64];
        float m = fmaxf(s0, s1);
        #pragma unroll
        for (int off = 32; off; off >>= 1) m = fmaxf(m, __shfl_xor(m, off, 64));
        float w0 = __expf(s0 - m), w1 = __expf(s1 - m);
        sc[lane] = w0; sc[lane + 64] = w1;
        float l = w0 + w1;
        #pragma unroll
        for (int off = 32; off; off >>= 1) l += __shfl_xor(l, off, 64);
        if (lane == 0) { ml[0] = m; ml[1] = l; }
    }
    __syncthreads();
    // pass 2: weighted V sum + shifted V write
    const float* Vh = V    + (size_t)h * TT * HD;
    float*      nVh = newV + (size_t)h * TT * HD;
    float a0 = 0.f, a1 = 0.f, a2 = 0.f, a3 = 0.f;
    for (int kk = 0; kk < 16; ++kk) {
        int r = t0 + kk * 8 + wave * 2 + half;
        f4v vv = __builtin_nontemporal_load((const f4v*)(Vh + (size_t)r * HD + 4 * l31));
        float w = sc[r - t0];
        a0 += w * vv.x; a1 += w * vv.y; a2 += w * vv.z; a3 += w * vv.w;
        if (r != SINKN) {
            int dst = (r < SINKN) ? r : r - 1;
            __builtin_nontemporal_store(vv, (f4v*)(nVh + (size_t)dst * HD + 4 * l31));
        }
    }
    int g = wave * 2 + half;
    ctx8[g][4 * l31 + 0] = a0;
    ctx8[g][4 * l31 + 1] = a1;
    ctx8[g][4 * l31 + 2] = a2;
    ctx8[g][4 * l31 + 3] = a3;
    __syncthreads();
    float* pbE = partB + ((size_t)h * (NC + 1) + c) * PBSTR;
    if (tid < HD) {
        float s = 0.f;
        #pragma unroll
        for (int gg = 0; gg < 8; ++gg) s += ctx8[gg][tid];
        pbE[2 + tid] = s;
    }
    if (tid == 0) { pbE[0] = ml[0]; pbE[1] = ml[1]; }

    // c==0 blocks: reduce k_new/v_new, write cache slot TT-1, emit 65th entry
    if (c == 0) {
        float kd = 0.f, vd = 0.f;
        if (tid < HD) {
            const float* pk = partA + (size_t)(ICH) * D + (size_t)h * HD + tid;
            const float* pv = partA + (size_t)(2 * ICH) * D + (size_t)h * HD + tid;
            #pragma unroll
            for (int i = 0; i < ICH; ++i) {
                kd += pk[(size_t)i * D];
                vd += pv[(size_t)i * D];
            }
            __builtin_nontemporal_store(kd, newK + ((size_t)h * TT + (TT - 1)) * HD + tid);
            __builtin_nontemporal_store(vd, newV + ((size_t)h * TT + (TT - 1)) * HD + tid);
        }
        __syncthreads();             // ctx8 reads above are done; safe to reuse
        if (tid < HD) ctx8[0][tid] = qs[tid] * kd;
        __syncthreads();
        float* pbN = partB + ((size_t)h * (NC + 1) + NC) * PBSTR;
        if (tid < 64) {
            float s = ctx8[0][tid] + ctx8[0][tid + 64];
            #pragma unroll
            for (int off = 32; off; off >>= 1) s += __shfl_xor(s, off, 64);
            if (tid == 0) { pbN[0] = s * scale; pbN[1] = 1.0f; }
        }
        if (tid < HD) pbN[2 + tid] = vd;
    }
}

// ---------------- K3: fused combine-slice + out GEMV with atomic reduce ----------------
// grid = 8 jb * 64 ic = 512 blocks, block = 128
__global__ __launch_bounds__(128) void out_fused(
        const float* __restrict__ partB,
        const float* __restrict__ Wo,
        float* __restrict__ out) {
    int bid = blockIdx.x;
    int jb = bid >> 6;       // 0..7
    int ic = bid & 63;       // 0..63
    int tid = threadIdx.x;   // 0..127
    int h  = ic >> 1;        // rows [ic*64, ic*64+64) sit in one head
    int d0 = (ic & 1) * 64;

    __shared__ float marr[NC + 1], larr[NC + 1], wgt[NC + 1];
    __shared__ float ctx[64];
    __shared__ float Ls;

    const float* pb = partB + (size_t)h * (NC + 1) * PBSTR;
    if (tid <= NC) {
        marr[tid] = pb[tid * PBSTR];
        larr[tid] = pb[tid * PBSTR + 1];
    }
    __syncthreads();
    float M = marr[0];
    #pragma unroll
    for (int cc = 1; cc <= NC; ++cc) M = fmaxf(M, marr[cc]);
    if (tid <= NC) wgt[tid] = __expf(marr[tid] - M);
    __syncthreads();
    if (tid < 64) {
        float s = wgt[tid] * larr[tid] + ((tid == 0) ? wgt[NC] * larr[NC] : 0.f);
        #pragma unroll
        for (int off = 32; off; off >>= 1) s += __shfl_xor(s, off, 64);
        if (tid == 0) Ls = s;
    }
    __syncthreads();
    if (tid < 64) {
        const float* pc = pb + 2 + d0 + tid;
        float acc = 0.f;
        #pragma unroll
        for (int cc = 0; cc <= NC; ++cc) acc += wgt[cc] * pc[cc * PBSTR];
        ctx[tid] = acc / Ls;
    }
    __syncthreads();

    int j0 = jb * 512 + tid * 4;
    float4 acc = {0.f, 0.f, 0.f, 0.f};
    const float* Wp = Wo + (size_t)(ic * 64) * D + j0;
    #pragma unroll 16
    for (int i = 0; i < 64; ++i) {
        float4 w = *(const float4*)Wp;
        float xv = ctx[i];
        acc.x += xv * w.x; acc.y += xv * w.y;
        acc.z += xv * w.z; acc.w += xv * w.w;
        Wp += D;
    }
    atomicAdd(&out[j0 + 0], acc.x);
    atomicAdd(&out[j0 + 1], acc.y);
    atomicAdd(&out[j0 + 2], acc.z);
    atomicAdd(&out[j0 + 3], acc.w);
}

extern "C" void kernel_launch(void* const* d_in, const int* in_sizes, int n_in,
                              void* d_out, int out_size, void* d_ws, size_t ws_size,
                              hipStream_t stream) {
    const float* x  = (const float*)d_in[0];
    const float* cK = (const float*)d_in[1];
    const float* cV = (const float*)d_in[2];
    const float* Wq = (const float*)d_in[3];
    const float* Wk = (const float*)d_in[4];
    const float* Wv = (const float*)d_in[5];
    const float* Wo = (const float*)d_in[6];

    float* out  = (float*)d_out;
    float* newK = out + D;
    float* newV = newK + (size_t)NH * TT * HD;

    float* ws    = (float*)d_ws;
    float* partA = ws;                       // 3*ICH*D floats = 3 MB
    float* partB = partA + 3 * ICH * D;      // NH*(NC+1)*PBSTR

    qkv_partial<<<768,     256, 0, stream>>>(x, Wq, Wk, Wv, partA, out);
    attn_chunk <<<NH * NC, 256, 0, stream>>>(partA, cK, cV, newK, newV, partB);
    out_fused  <<<512,     128, 0, stream>>>(partB, Wo, out);
}